// Round 1
// baseline (57.786 us; speedup 1.0000x reference)
//
#include <hip/hip_runtime.h>

// RankingLoss: for each row, sum log_sigmoid(logit_i - logit_j) over ordered
// pairs with label_i - label_j > TOL; mean over rows.
// Identity used: lsig(-d) = lsig(d) - d, so each UNORDERED pair needs one
// exp + one log:  C = valid * lsig(d) - flip * d
//   valid = |lab_i - lab_j| > TOL   (some ordering contributes)
//   flip  = (lab_i - lab_j) < -TOL  (the contributing ordering is (j,i))
// Pair enumeration: circulant j = (i+k) mod N, k in [1,1024]; k in [1,1023]
// hits each unordered pair exactly once; k=1024 hits each twice (contribution
// symmetric) -> subtract half of it afterwards.

#define NN 2048
#define BB 64
#define TOL 0.01f
#define BLK 256
#define NBLK_PER_ROW 16              // 8 i-chunks x 2 k-chunks
#define GRID (BB * NBLK_PER_ROW)     // 1024

__device__ float g_partials[GRID];

__global__ __launch_bounds__(BLK) void rank_main(const float* __restrict__ logits,
                                                 const float* __restrict__ labels) {
    __shared__ float2 sp[NN + NN / 2];   // 3072 entries, 24 KB (duplicated wrap)
    const int bid = blockIdx.x;
    const int row = bid >> 4;
    const int sub = bid & 15;
    const int ichunk = sub >> 1;
    const int kc = sub & 1;

    const float* lg = logits + (size_t)row * NN;
    const float* lb = labels + (size_t)row * NN;
    for (int jj = threadIdx.x; jj < NN + NN / 2; jj += BLK) {
        int j = jj & (NN - 1);
        sp[jj] = make_float2(lg[j], lb[j]);
    }
    __syncthreads();

    const int i = ichunk * BLK + threadIdx.x;
    const float li  = sp[i].x;
    const float lai = sp[i].y;

    float accL = 0.0f;   // sum of log2(1 + exp(-d)) over valid pairs
    float accD = 0.0f;   // sum of d over flipped pairs

    const int kbeg = kc * 512 + 1;   // kc=0: k=1..512 ; kc=1: k=513..1024
#pragma unroll 4
    for (int k = kbeg; k < kbeg + 512; ++k) {
        float2 pj = sp[i + k];
        float d   = li  - pj.x;
        float ld  = lai - pj.y;
        bool valid = fabsf(ld) > TOL;
        bool flip  = ld < -TOL;
        float t  = __expf(-d);          // v_mul + v_exp ; |d| <= ~11 so no overflow
        float l2 = __log2f(1.0f + t);   // v_add + v_log
        accL += valid ? l2 : 0.0f;
        accD += flip ? d : 0.0f;
    }
    if (kc == 1) {
        // k=1024 pairs were visited at full weight from both endpoints; each
        // visit should count half. Remove the surplus half here.
        float2 pj = sp[i + 1024];
        float d   = li  - pj.x;
        float ld  = lai - pj.y;
        bool valid = fabsf(ld) > TOL;
        bool flip  = ld < -TOL;
        float t  = __expf(-d);
        float l2 = __log2f(1.0f + t);
        accL -= 0.5f * (valid ? l2 : 0.0f);
        accD -= 0.5f * (flip ? d : 0.0f);
    }

    // contribution = -ln2 * accL - accD
    float v = -0.69314718055994531f * accL - accD;

    // block reduction: wave shfl then cross-wave via LDS
    for (int off = 32; off > 0; off >>= 1) v += __shfl_down(v, off);
    __shared__ float swave[BLK / 64];
    const int wid  = threadIdx.x >> 6;
    const int lane = threadIdx.x & 63;
    if (lane == 0) swave[wid] = v;
    __syncthreads();
    if (threadIdx.x == 0)
        g_partials[bid] = swave[0] + swave[1] + swave[2] + swave[3];
}

__global__ __launch_bounds__(BLK) void rank_final(float* __restrict__ out) {
    float v = 0.0f;
    for (int idx = threadIdx.x; idx < GRID; idx += BLK) v += g_partials[idx];
    for (int off = 32; off > 0; off >>= 1) v += __shfl_down(v, off);
    __shared__ float swave[BLK / 64];
    const int wid  = threadIdx.x >> 6;
    const int lane = threadIdx.x & 63;
    if (lane == 0) swave[wid] = v;
    __syncthreads();
    if (threadIdx.x == 0)
        out[0] = (swave[0] + swave[1] + swave[2] + swave[3]) * (1.0f / BB);
}

extern "C" void kernel_launch(void* const* d_in, const int* in_sizes, int n_in,
                              void* d_out, int out_size, void* d_ws, size_t ws_size,
                              hipStream_t stream) {
    const float* logits = (const float*)d_in[0];
    const float* labels = (const float*)d_in[1];
    float* out = (float*)d_out;
    (void)in_sizes; (void)n_in; (void)out_size; (void)d_ws; (void)ws_size;

    rank_main<<<GRID, BLK, 0, stream>>>(logits, labels);
    rank_final<<<1, BLK, 0, stream>>>(out);
}

// Round 2
// 38.690 us; speedup vs baseline: 1.4936x; 1.4936x over previous
//
#include <hip/hip_runtime.h>

// RankingLoss: mean over rows of sum over ordered pairs (label_i-label_j>TOL)
// of log_sigmoid(logit_i - logit_j).
//
// Per unordered pair with ds = (logit_i-logit_j)*log2(e), ld = label_i-label_j:
//   invalid (|ld|<=TOL): 0
//   normal  (ld > TOL):  -ln2 * log2(1 + 2^{-ds})
//   flipped (ld < -TOL): -ln2 * log2(1 + 2^{+ds})
// Unified: a = flip ? ds : -ds; t = valid ? 2^a : 0; term = (1+t).
// Accumulate log2 of products of 4 terms (one v_log per 4 pairs).
//
// Pair enumeration: circulant j=(i+k) mod N, k in [1,1024]; k in [1,1023] hits
// each unordered pair once, k=1024 twice -> subtract half of the k=1024 term.

#define NN 2048
#define BB 64
#define TOL 0.01f
#define BLK 256
#define KCHUNKS 4
#define ICHUNKS 8
#define NBLK_PER_ROW (KCHUNKS * ICHUNKS)   // 32
#define GRID (BB * NBLK_PER_ROW)           // 2048
#define LOG2E 1.4426950408889634f

__device__ float g_partials[GRID];

__global__ __launch_bounds__(BLK) void rank_main(const float* __restrict__ logits,
                                                 const float* __restrict__ labels) {
    __shared__ float2 spj[512];
    const int bid = blockIdx.x;
    const int row = bid >> 5;
    const int sub = bid & 31;
    const int ic = sub >> 2;     // 0..7
    const int kc = sub & 3;      // 0..3

    const float* lg = logits + (size_t)row * NN;
    const float* lb = labels + (size_t)row * NN;
    const int ibeg = ic * BLK;
    const int kbeg = kc * 256 + 1;
    const int jbeg = ibeg + kbeg;

    // stage j-window: indices jbeg .. jbeg+510 (mod N), logits pre-scaled by log2e
    for (int x = threadIdx.x; x < 512; x += BLK) {
        int j = (jbeg + x) & (NN - 1);
        spj[x] = make_float2(lg[j] * LOG2E, lb[j]);
    }
    __syncthreads();

    const int i = ibeg + threadIdx.x;
    const float li_s = lg[i] * LOG2E;
    const float lai  = lb[i];

    float accL = 0.0f;   // sum of log2-terms
#pragma unroll 4
    for (int kk0 = 0; kk0 < 256; kk0 += 4) {
        float prod = 1.0f;
#pragma unroll
        for (int u = 0; u < 4; ++u) {
            float2 pj = spj[threadIdx.x + kk0 + u];
            float ds = li_s - pj.x;
            float ld = lai - pj.y;
            float a  = (ld < -TOL) ? ds : -ds;
            float t  = __builtin_amdgcn_exp2f(a);
            float tm = (fabsf(ld) > TOL) ? t : 0.0f;
            prod = fmaf(tm, prod, prod);        // prod *= (1 + tm)
        }
        accL += __builtin_amdgcn_logf(prod);     // v_log_f32 = log2
    }
    if (kc == 3) {
        // k=1024 (kk=255) was visited at full weight from both endpoints; each
        // visit should count half -> remove the surplus half here.
        float2 pj = spj[threadIdx.x + 255];
        float ds = li_s - pj.x;
        float ld = lai - pj.y;
        float a  = (ld < -TOL) ? ds : -ds;
        float t  = __builtin_amdgcn_exp2f(a);
        float tm = (fabsf(ld) > TOL) ? t : 0.0f;
        accL -= 0.5f * __builtin_amdgcn_logf(1.0f + tm);
    }

    float v = -0.69314718055994531f * accL;

    for (int off = 32; off > 0; off >>= 1) v += __shfl_down(v, off);
    __shared__ float swave[BLK / 64];
    const int wid  = threadIdx.x >> 6;
    const int lane = threadIdx.x & 63;
    if (lane == 0) swave[wid] = v;
    __syncthreads();
    if (threadIdx.x == 0)
        g_partials[bid] = swave[0] + swave[1] + swave[2] + swave[3];
}

__global__ __launch_bounds__(BLK) void rank_final(float* __restrict__ out) {
    float v = 0.0f;
    for (int idx = threadIdx.x; idx < GRID; idx += BLK) v += g_partials[idx];
    for (int off = 32; off > 0; off >>= 1) v += __shfl_down(v, off);
    __shared__ float swave[BLK / 64];
    const int wid  = threadIdx.x >> 6;
    const int lane = threadIdx.x & 63;
    if (lane == 0) swave[wid] = v;
    __syncthreads();
    if (threadIdx.x == 0)
        out[0] = (swave[0] + swave[1] + swave[2] + swave[3]) * (1.0f / BB);
}

extern "C" void kernel_launch(void* const* d_in, const int* in_sizes, int n_in,
                              void* d_out, int out_size, void* d_ws, size_t ws_size,
                              hipStream_t stream) {
    const float* logits = (const float*)d_in[0];
    const float* labels = (const float*)d_in[1];
    float* out = (float*)d_out;
    (void)in_sizes; (void)n_in; (void)out_size; (void)d_ws; (void)ws_size;

    rank_main<<<GRID, BLK, 0, stream>>>(logits, labels);
    rank_final<<<1, BLK, 0, stream>>>(out);
}